// Round 8
// baseline (507.732 us; speedup 1.0000x reference)
//
#include <hip/hip_runtime.h>
#include <math.h>

// Problem constants (from reference setup_inputs)
#define BBATCH 16
#define NPTS   4096
#define MPTS   1024
#define C1c    128
#define C2c    256
#define CINc   384
#define H1c    256
#define H2c    128
#define TN     64

typedef _Float16 f16x8 __attribute__((ext_vector_type(8)));
typedef _Float16 f16x4 __attribute__((ext_vector_type(4)));
typedef float    f32x4 __attribute__((ext_vector_type(4)));

// Raw barrier: drain LDS ops only; global prefetch loads stay in flight.
#define BAR() do { asm volatile("s_waitcnt lgkmcnt(0)" ::: "memory"); \
                   __builtin_amdgcn_s_barrier(); } while (0)

// ---- LDS layout (bytes) ---------------------------------------------------
// R14 lesson: 51,200 B never fit 3 blocks/CU (occupancy flat at 16 waves/CU) —
// usable LDS/CU < 153.6 KB. This round shrinks the block to 34,816 B so even a
// 128-KB-usable CU fits 3 (104 KB) and a full 160-KB CU fits 4 (139 KB).
//   union [0,32768):
//     phase A: inv dbuf 2 x [2 cc][4 nt][64 lane][8 f16] = 16384 B  (64-m chunks)
//              s_xyz2 [1024][3] f32 = 12288 B at 16384 (dead after last gen)
//     phase B: s_X frags [8 kq][4 nt][64][8] f16 = 32768 B (interp only; p1 is
//              gathered direct-from-global in phase B — its 32 KB tile is L1-sized)
//     phase C: s_H frags [8 oc][4 nt][64][8] f16 = 32768 B
//   s_red 512 f32 at 32768 (disjoint from union -> no extra barrier vs interp)
#define INV_HALF   4096            // f16 elems per inv buffer (8192 B)
#define OFF_XYZ2   16384
#define OFF_RED    32768
#define SMEM_BYTES 34816

// ---- fragment-swizzled workspace layout (f16 elements), UNCHANGED ----
#define NFRAG_P2  (BBATCH * 32 * 16 * 64)        // 524288
#define NFRAG_W1  (16 * 12 * 64)                 // 12288
#define NFRAG_W2  (8 * 8 * 64)                   // 4096
#define WS_P2S  0
#define WS_W1S  (NFRAG_P2 * 8)                   // 4194304
#define WS_W2S  (WS_W1S + NFRAG_W1 * 8)
#define WS_F16_TOTAL (WS_W2S + NFRAG_W2 * 8)     // 4325376 f16 = 8650752 B

// ---------------------------------------------------------------------------
// pre-pass: convert + swizzle p2 / W1 / W2 into fragment-contiguous f16
__global__ __launch_bounds__(256) void cvt_swz(
    const float* __restrict__ p2, const float* __restrict__ W1,
    const float* __restrict__ W2, _Float16* __restrict__ ws)
{
    const int t = blockIdx.x * 256 + threadIdx.x;   // one fragment (8 f16) per thread
    const float* src;
    _Float16* dst;
    if (t < NFRAG_P2) {
        const int lane = t & 63, wt = (t >> 6) & 15, s = (t >> 10) & 31, b = t >> 15;
        const int c = wt * 16 + (lane & 15);
        const int m = s * 32 + (lane >> 4) * 8;
        src = p2 + ((size_t)(b * C2c + c)) * MPTS + m;
        dst = ws + WS_P2S + (size_t)t * 8;
    } else if (t < NFRAG_P2 + NFRAG_W1) {
        const int u = t - NFRAG_P2;
        const int lane = u & 63, kc = (u >> 6) % 12, wt = (u >> 6) / 12;
        const int o = wt * 16 + (lane & 15);
        const int k = kc * 32 + (lane >> 4) * 8;
        src = W1 + (size_t)o * CINc + k;
        dst = ws + WS_W1S + (size_t)u * 8;
    } else {
        const int v = t - NFRAG_P2 - NFRAG_W1;
        const int lane = v & 63, oc = (v >> 6) & 7, wt2 = v >> 9;
        const int o = wt2 * 16 + (lane & 15);
        const int k = oc * 32 + (lane >> 4) * 8;
        src = W2 + (size_t)o * H1c + k;
        dst = ws + WS_W2S + (size_t)v * 8;
    }
    const float4 a0 = *(const float4*)(src);
    const float4 a1 = *(const float4*)(src + 4);
    f16x8 h;
    h[0] = (_Float16)a0.x; h[1] = (_Float16)a0.y; h[2] = (_Float16)a0.z; h[3] = (_Float16)a0.w;
    h[4] = (_Float16)a1.x; h[5] = (_Float16)a1.y; h[6] = (_Float16)a1.z; h[7] = (_Float16)a1.w;
    *(f16x8*)dst = h;
}

// ---------------------------------------------------------------------------
// R16: small-footprint block for real 3-4 blocks/CU residency.
//  - 64-m super-chunks (17 barriers; R12/R13 proved barrier count ~free).
//    gen mapping: thread (w,L): n=L, m = ss*64 + w*8 + i ->
//    frag cc = w>>2, k-slot = w&3, nt = L>>4, lane = L&15: one f16x8 store.
//  - p1 gathered directly from global inside phase B kc 0..3 (tile is L1-sized;
//    redundancy absorbed) -> no p1 staging, no peeled-A machinery.
//  - s_red above the union; interp needs no extra barrier (disjoint).
//  - Everything proven kept: frag layouts, ring-4 distance-2 A-prefetch (static
//    slots via 2x-unrolled ss pairs), lgkm-only barriers, setprio, XCD swizzle.
template <bool F16P>
__global__ __launch_bounds__(512, 8) void fp_mfma15(
    const float* __restrict__ xyz1, const float* __restrict__ xyz2,
    const float* __restrict__ p1,   const float* __restrict__ p2,
    const float* __restrict__ W1,   const float* __restrict__ b1v,
    const float* __restrict__ W2,   const float* __restrict__ b2v,
    const _Float16* __restrict__ p2s, const _Float16* __restrict__ W1s,
    const _Float16* __restrict__ W2s,
    float* __restrict__ out)
{
    __shared__ __align__(16) char smem[SMEM_BYTES];
    _Float16* s_inv  = (_Float16*)smem;
    _Float16* s_X    = (_Float16*)smem;
    _Float16* s_H    = (_Float16*)smem;
    float*    s_xyz2 = (float*)(smem + OFF_XYZ2);
    float*    s_red  = (float*)(smem + OFF_RED);

    const int tid  = threadIdx.x;
    const int w    = tid >> 6;    // wave 0..7
    const int L    = tid & 63;
    const int quad = L >> 4;
    const int l16  = L & 15;

    // XCD swizzle: each XCD sees 2 batches -> p2s working set (1 MB) L2-resident
    const int id = blockIdx.x;            // 1024 blocks
    const int b  = (id & 7) * 2 + ((id >> 3) & 1);
    const int n0 = (id >> 4) * TN;

    const float* __restrict__ z2b = xyz2 + (size_t)b * MPTS * 3;
    const float* __restrict__ p2b = p2   + (size_t)b * C2c * MPTS;
    const _Float16* __restrict__ p2sb =
        F16P ? (p2s + (((size_t)b * 32 * 16 + (size_t)w * 2) * 64 + L) * 8) : (const _Float16*)nullptr;

    // stage xyz2 (12 KB, coalesced f32x4)
    for (int i = tid; i < MPTS * 3 / 4; i += 512)
        ((f32x4*)s_xyz2)[i] = ((const f32x4*)z2b)[i];

    const float x1x = xyz1[((size_t)b * NPTS + n0 + L) * 3 + 0];
    const float x1y = xyz1[((size_t)b * NPTS + n0 + L) * 3 + 1];
    const float x1z = xyz1[((size_t)b * NPTS + n0 + L) * 3 + 2];

    f32x4 acc[2][4];   // [ct][nt]: row c = w*32+ct*16+quad*4+r, col n = nt*16+l16
    #pragma unroll
    for (int ct = 0; ct < 2; ++ct)
        #pragma unroll
        for (int nt = 0; nt < 4; ++nt)
            acc[ct][nt] = (f32x4){0.f, 0.f, 0.f, 0.f};

    float ssum = 0.f;
    f16x8 Aa[4][2];    // A-frag ring, slot = global chunk & 3 (distance 2)

    auto loadA = [&](int s, f16x8 dst[2]) {
        if (F16P) {
            const _Float16* ap = p2sb + (size_t)s * (16 * 64 * 8);
            #pragma unroll
            for (int ct = 0; ct < 2; ++ct)
                dst[ct] = *(const f16x8*)(ap + (size_t)ct * (64 * 8));
        } else {
            const float* ap = p2b + (size_t)(w * 32 + l16) * MPTS + s * 32 + quad * 8;
            #pragma unroll
            for (int ct = 0; ct < 2; ++ct) {
                const float4 a0 = *(const float4*)(ap + (size_t)ct * (16 * MPTS));
                const float4 a1 = *(const float4*)(ap + (size_t)ct * (16 * MPTS) + 4);
                f16x8 h;
                h[0] = (_Float16)a0.x; h[1] = (_Float16)a0.y; h[2] = (_Float16)a0.z; h[3] = (_Float16)a0.w;
                h[4] = (_Float16)a1.x; h[5] = (_Float16)a1.y; h[6] = (_Float16)a1.z; h[7] = (_Float16)a1.w;
                dst[ct] = h;
            }
        }
    };

    // gen the 64-m super-chunk ss_ into buffer (ss_&1): thread (w,L): n = L,
    // m = ss_*64 + w*8 + i -> frag cc=w>>2, k-slot=w&3, nt=L>>4, lane=L&15.
    auto gen = [&](int ss_) {
        _Float16* buf = s_inv + (ss_ & 1) * INV_HALF;
        const float* zp = s_xyz2 + (size_t)(ss_ * 64 + w * 8) * 3;   // wave-uniform, 16B-aligned
        f32x4 zr[6];
        #pragma unroll
        for (int j = 0; j < 6; ++j) zr[j] = ((const f32x4*)zp)[j];
        const float* zv = (const float*)zr;
        f16x8 iv;
        #pragma unroll
        for (int i = 0; i < 8; ++i) {
            const float dx = x1x - zv[3 * i + 0];
            const float dy = x1y - zv[3 * i + 1];
            const float dz = x1z - zv[3 * i + 2];
            const float d2 = fmaf(dx, dx, fmaf(dy, dy, fmaf(dz, dz, 1e-12f)));
            const float inv = __builtin_amdgcn_rsqf(d2);
            ssum += inv;
            iv[i] = (_Float16)inv;
        }
        *(f16x8*)(buf + ((((w >> 2) * 4 + (L >> 4)) * 64) + (w & 3) * 16 + l16) * 8) = iv;
    };

    // one chunk's MFMA cluster (cc, A-slot are compile-time literals)
    auto mmac = [&](const _Float16* buf, int cc, f16x8 A_[2]) {
        __builtin_amdgcn_s_setprio(1);
        #pragma unroll
        for (int nt = 0; nt < 4; ++nt) {
            const f16x8 bf = *(const f16x8*)(buf + ((cc * 4 + nt) * 64 + L) * 8);
            #pragma unroll
            for (int ct = 0; ct < 2; ++ct)
                acc[ct][nt] = __builtin_amdgcn_mfma_f32_16x16x32_f16(A_[ct], bf, acc[ct][nt], 0, 0, 0);
        }
        __builtin_amdgcn_s_setprio(0);
    };

    loadA(0, Aa[0]);
    loadA(1, Aa[1]);
    BAR();             // xyz2 staged (lgkm drain; A-prefetch stays in flight)
    gen(0);
    BAR();             // super-chunk 0 visible

    // ---- phase A: 16 super-chunks as 8 even/odd pairs (static ring slots) ----
    for (int sp = 0; sp < 8; ++sp) {
        const int s4 = sp * 4;
        // ss = 2sp (buffer 0, chunks s4, s4+1 in slots 0,1)
        if (s4 + 2 < 32) loadA(s4 + 2, Aa[2]);
        gen(2 * sp + 1);                        // writes buffer 1 (2sp+1 <= 15)
        mmac(s_inv, 0, Aa[0]);
        if (s4 + 3 < 32) loadA(s4 + 3, Aa[3]);
        mmac(s_inv, 1, Aa[1]);
        BAR();
        // ss = 2sp+1 (buffer 1, chunks s4+2, s4+3 in slots 2,3)
        if (s4 + 4 < 32) loadA(s4 + 4, Aa[0]);
        if (2 * sp + 2 < 16) gen(2 * sp + 2);   // writes buffer 0 (reads drained)
        mmac(s_inv + INV_HALF, 0, Aa[2]);
        if (s4 + 5 < 32) loadA(s4 + 5, Aa[1]);
        mmac(s_inv + INV_HALF, 1, Aa[3]);
        BAR();
    }

    // ---- S[n] reduction over the 8 wave partials; recip in s_red[0..63] ----
    s_red[tid] = ssum;
    BAR();
    if (tid < 64) {
        float s = 0.f;
        #pragma unroll
        for (int wv = 0; wv < 8; ++wv) s += s_red[wv * 64 + tid];
        s_red[tid] = 1.0f / s;
    }
    BAR();   // recip ready; phase-A scratch dead -> interp overlay safe

    // phase-B prefetch issued now: flies across the interp work + barrier
    f16x8 afP[2][2];
    auto loadW1 = [&](int kc, f16x8 dst[2]) {
        if (F16P) {
            const _Float16* wp = W1s + (((size_t)(w * 2) * 12 + kc) * 64 + L) * 8;
            #pragma unroll
            for (int ct = 0; ct < 2; ++ct)
                dst[ct] = *(const f16x8*)(wp + (size_t)ct * (12 * 64 * 8));
        } else {
            const float* wp = W1 + (size_t)(w * 32 + l16) * CINc + kc * 32 + quad * 8;
            #pragma unroll
            for (int ct = 0; ct < 2; ++ct) {
                const float4 a0 = *(const float4*)(wp + ct * (16 * CINc));
                const float4 a1 = *(const float4*)(wp + ct * (16 * CINc) + 4);
                f16x8 h;
                h[0] = (_Float16)a0.x; h[1] = (_Float16)a0.y; h[2] = (_Float16)a0.z; h[3] = (_Float16)a0.w;
                h[4] = (_Float16)a1.x; h[5] = (_Float16)a1.y; h[6] = (_Float16)a1.z; h[7] = (_Float16)a1.w;
                dst[ct] = h;
            }
        }
    };
    loadW1(0, afP[0]);

    // interp -> s_X frags kq = w (bytes [0,32K) overlaying dead inv dbuf + xyz2).
    // value (n = nt*16+l16, c = w*32+ct*16+quad*4+r):
    //   lane slot = (ct*2 + (quad>>1))*16 + l16, elem offset (quad&1)*4 + r.
    // s_red is ABOVE the union -> rn4 reads race nothing.
    {
        float rn4[4];
        #pragma unroll
        for (int nt = 0; nt < 4; ++nt) rn4[nt] = s_red[nt * 16 + l16];
        #pragma unroll
        for (int ct = 0; ct < 2; ++ct) {
            const int lp = (ct * 2 + (quad >> 1)) * 16 + l16;
            const int jo = (quad & 1) * 4;
            #pragma unroll
            for (int nt = 0; nt < 4; ++nt) {
                const f32x4 v = acc[ct][nt];
                const float r = rn4[nt];
                f16x4 hv;
                hv[0] = (_Float16)(v[0] * r);
                hv[1] = (_Float16)(v[1] * r);
                hv[2] = (_Float16)(v[2] * r);
                hv[3] = (_Float16)(v[3] * r);
                *(f16x4*)(s_X + (((size_t)(w * 4 + nt)) * 64 + lp) * 8 + jo) = hv;
            }
        }
    }
    BAR();   // interp frags complete; W1 frag-0 still in flight

    // ---------------- Phase B: h = relu(W1 @ [p1; U] + b1), K=384 ----------
    // kc 0..3: B-frags gathered per-lane from p1 (32-KB tile, L1-resident);
    // kc 4..11: contiguous s_X frag reads.
    f32x4 hacc[2][4];
    #pragma unroll
    for (int ct = 0; ct < 2; ++ct)
        #pragma unroll
        for (int nt = 0; nt < 4; ++nt)
            hacc[ct][nt] = (f32x4){0.f, 0.f, 0.f, 0.f};

    const float* p1base = p1 + (size_t)b * C1c * NPTS + n0;
    #pragma unroll
    for (int kc = 0; kc < 12; ++kc) {
        if (kc + 1 < 12) loadW1(kc + 1, afP[(kc + 1) & 1]);
        __builtin_amdgcn_s_setprio(1);
        #pragma unroll
        for (int nt = 0; nt < 4; ++nt) {
            f16x8 bf;
            if (kc < 4) {
                const float* pp = p1base + (size_t)(kc * 32 + quad * 8) * NPTS + nt * 16 + l16;
                float t[8];
                #pragma unroll
                for (int j = 0; j < 8; ++j) t[j] = pp[(size_t)j * NPTS];
                #pragma unroll
                for (int j = 0; j < 8; ++j) bf[j] = (_Float16)t[j];
            } else {
                bf = *(const f16x8*)(s_X + (((size_t)((kc - 4) * 4 + nt)) * 64 + L) * 8);
            }
            #pragma unroll
            for (int ct = 0; ct < 2; ++ct)
                hacc[ct][nt] = __builtin_amdgcn_mfma_f32_16x16x32_f16(afP[kc & 1][ct], bf, hacc[ct][nt], 0, 0, 0);
        }
        __builtin_amdgcn_s_setprio(0);
    }

    BAR();   // all s_X reads done before overlaying s_H

    // phase-C prefetch issued now: flies across h-stage + barrier
    f16x8 afP2[2];
    auto loadW2 = [&](int oc, f16x8& dst) {
        if (F16P) {
            dst = *(const f16x8*)(W2s + (((size_t)(w * 8 + oc)) * 64 + L) * 8);
        } else {
            const float* wp = W2 + (size_t)(w * 16 + l16) * H1c + oc * 32 + quad * 8;
            const float4 a0 = *(const float4*)(wp);
            const float4 a1 = *(const float4*)(wp + 4);
            f16x8 h;
            h[0] = (_Float16)a0.x; h[1] = (_Float16)a0.y; h[2] = (_Float16)a0.z; h[3] = (_Float16)a0.w;
            h[4] = (_Float16)a1.x; h[5] = (_Float16)a1.y; h[6] = (_Float16)a1.z; h[7] = (_Float16)a1.w;
            dst = h;
        }
    };
    loadW2(0, afP2[0]);

    // bias + relu + stage h -> s_H frag layout (oq = w, same slot math as interp)
    {
        f32x4 bb[2];
        #pragma unroll
        for (int ct = 0; ct < 2; ++ct)
            bb[ct] = *(const f32x4*)(b1v + w * 32 + ct * 16 + quad * 4);
        #pragma unroll
        for (int ct = 0; ct < 2; ++ct) {
            const int lp = (ct * 2 + (quad >> 1)) * 16 + l16;
            const int jo = (quad & 1) * 4;
            #pragma unroll
            for (int nt = 0; nt < 4; ++nt) {
                const f32x4 v = hacc[ct][nt];
                f16x4 hv;
                hv[0] = (_Float16)fmaxf(v[0] + bb[ct][0], 0.f);
                hv[1] = (_Float16)fmaxf(v[1] + bb[ct][1], 0.f);
                hv[2] = (_Float16)fmaxf(v[2] + bb[ct][2], 0.f);
                hv[3] = (_Float16)fmaxf(v[3] + bb[ct][3], 0.f);
                *(f16x4*)(s_H + (((size_t)(w * 4 + nt)) * 64 + lp) * 8 + jo) = hv;
            }
        }
    }
    BAR();

    // ---------------- Phase C: out = relu(W2 @ h + b2), K=256 --------------
    f32x4 oacc[4];
    #pragma unroll
    for (int nt = 0; nt < 4; ++nt)
        oacc[nt] = (f32x4){0.f, 0.f, 0.f, 0.f};

    #pragma unroll
    for (int oc = 0; oc < 8; ++oc) {
        if (oc + 1 < 8) loadW2(oc + 1, afP2[(oc + 1) & 1]);
        __builtin_amdgcn_s_setprio(1);
        #pragma unroll
        for (int nt = 0; nt < 4; ++nt) {
            const f16x8 bf = *(const f16x8*)(s_H + (((size_t)(oc * 4 + nt)) * 64 + L) * 8);
            oacc[nt] = __builtin_amdgcn_mfma_f32_16x16x32_f16(afP2[oc & 1], bf, oacc[nt], 0, 0, 0);
        }
        __builtin_amdgcn_s_setprio(0);
    }

    // epilogue: bias + relu + store (o = w*16 + quad*4 + j)
    {
        const f32x4 bb2 = *(const f32x4*)(b2v + w * 16 + quad * 4);
        #pragma unroll
        for (int nt = 0; nt < 4; ++nt) {
            float* op = out + ((size_t)b * H2c + w * 16 + quad * 4) * NPTS
                            + n0 + nt * 16 + l16;
            #pragma unroll
            for (int j = 0; j < 4; ++j)
                op[(size_t)j * NPTS] = fmaxf(oacc[nt][j] + bb2[j], 0.f);
        }
    }
}

extern "C" void kernel_launch(void* const* d_in, const int* in_sizes, int n_in,
                              void* d_out, int out_size, void* d_ws, size_t ws_size,
                              hipStream_t stream) {
    (void)in_sizes; (void)n_in; (void)out_size;
    const float* xyz1 = (const float*)d_in[0];
    const float* xyz2 = (const float*)d_in[1];
    const float* p1   = (const float*)d_in[2];
    const float* p2   = (const float*)d_in[3];
    const float* W1   = (const float*)d_in[4];
    const float* b1   = (const float*)d_in[5];
    const float* W2   = (const float*)d_in[6];
    const float* b2   = (const float*)d_in[7];
    float* out = (float*)d_out;

    dim3 grid(BBATCH * (NPTS / TN));   // 1024 blocks; 4/CU resident = 1 exact round
    dim3 block(512);
    if (ws_size >= (size_t)WS_F16_TOTAL * 2) {
        _Float16* ws = (_Float16*)d_ws;
        const int nswz = NFRAG_P2 + NFRAG_W1 + NFRAG_W2;   // 540672 = 2112 * 256
        cvt_swz<<<dim3(nswz / 256), dim3(256), 0, stream>>>(p2, W1, W2, ws);
        fp_mfma15<true><<<grid, block, 0, stream>>>(xyz1, xyz2, p1, p2, W1, b1, W2, b2,
                                                    ws + WS_P2S, ws + WS_W1S, ws + WS_W2S, out);
    } else {
        fp_mfma15<false><<<grid, block, 0, stream>>>(xyz1, xyz2, p1, p2, W1, b1, W2, b2,
                                                     nullptr, nullptr, nullptr, out);
    }
}

// Round 10
// 166.492 us; speedup vs baseline: 3.0496x; 3.0496x over previous
//
#include <hip/hip_runtime.h>
#include <math.h>

// Problem constants (from reference setup_inputs)
#define BBATCH 16
#define NPTS   4096
#define MPTS   1024
#define C1c    128
#define C2c    256
#define CINc   384
#define H1c    256
#define H2c    128
#define TN     64

typedef _Float16 f16x8 __attribute__((ext_vector_type(8)));
typedef _Float16 f16x4 __attribute__((ext_vector_type(4)));
typedef float    f32x4 __attribute__((ext_vector_type(4)));

// Raw barrier: drain LDS ops only; global prefetch loads stay in flight.
#define BAR() do { asm volatile("s_waitcnt lgkmcnt(0)" ::: "memory"); \
                   __builtin_amdgcn_s_barrier(); } while (0)

// ---- LDS layout (bytes) ---------------------------------------------------
// union [0,49152):
//   phase A: inv dbuf 2 x [4 cc][4 nt][64 lane][8 f16] = 32768 B
//            s_xyz2 [1024][3] f32 = 12288 B at 32768 (dead after last gen)
//   phase B: s_X frags [12 kc][4 nt][64][8] f16 = 49152 B
//   phase C: s_H frags [8 oc][4 nt][64][8] f16 = 32768 B
// s_red 512 f32 at 49152 (recip overlaid in first 64)
// Total 51200 B -> 2 blocks/CU, 16 waves/CU. (R14's 3-block attempt showed
// occupancy is pinned here regardless of launch_bounds; R16's small-LDS
// restructure spilled catastrophically. This is the proven-best config.)
#define INV_HALF   8192            // f16 elems per inv buffer (16384 B)
#define OFF_XYZ2   32768
#define OFF_RED    49152
#define SMEM_BYTES 51200

// ---- fragment-swizzled workspace layout (f16 elements), unchanged ----
#define NFRAG_P2  (BBATCH * 32 * 16 * 64)        // 524288
#define NFRAG_W1  (16 * 12 * 64)                 // 12288
#define NFRAG_W2  (8 * 8 * 64)                   // 4096
#define WS_P2S  0
#define WS_W1S  (NFRAG_P2 * 8)                   // 4194304
#define WS_W2S  (WS_W1S + NFRAG_W1 * 8)
#define WS_F16_TOTAL (WS_W2S + NFRAG_W2 * 8)     // 4325376 f16 = 8650752 B

// ---------------------------------------------------------------------------
// pre-pass: convert + swizzle p2 / W1 / W2 into fragment-contiguous f16
__global__ __launch_bounds__(256) void cvt_swz(
    const float* __restrict__ p2, const float* __restrict__ W1,
    const float* __restrict__ W2, _Float16* __restrict__ ws)
{
    const int t = blockIdx.x * 256 + threadIdx.x;   // one fragment (8 f16) per thread
    const float* src;
    _Float16* dst;
    if (t < NFRAG_P2) {
        const int lane = t & 63, wt = (t >> 6) & 15, s = (t >> 10) & 31, b = t >> 15;
        const int c = wt * 16 + (lane & 15);
        const int m = s * 32 + (lane >> 4) * 8;
        src = p2 + ((size_t)(b * C2c + c)) * MPTS + m;
        dst = ws + WS_P2S + (size_t)t * 8;
    } else if (t < NFRAG_P2 + NFRAG_W1) {
        const int u = t - NFRAG_P2;
        const int lane = u & 63, kc = (u >> 6) % 12, wt = (u >> 6) / 12;
        const int o = wt * 16 + (lane & 15);
        const int k = kc * 32 + (lane >> 4) * 8;
        src = W1 + (size_t)o * CINc + k;
        dst = ws + WS_W1S + (size_t)u * 8;
    } else {
        const int v = t - NFRAG_P2 - NFRAG_W1;
        const int lane = v & 63, oc = (v >> 6) & 7, wt2 = v >> 9;
        const int o = wt2 * 16 + (lane & 15);
        const int k = oc * 32 + (lane >> 4) * 8;
        src = W2 + (size_t)o * H1c + k;
        dst = ws + WS_W2S + (size_t)v * 8;
    }
    const float4 a0 = *(const float4*)(src);
    const float4 a1 = *(const float4*)(src + 4);
    f16x8 h;
    h[0] = (_Float16)a0.x; h[1] = (_Float16)a0.y; h[2] = (_Float16)a0.z; h[3] = (_Float16)a0.w;
    h[4] = (_Float16)a1.x; h[5] = (_Float16)a1.y; h[6] = (_Float16)a1.z; h[7] = (_Float16)a1.w;
    *(f16x8*)dst = h;
}

// ---------------------------------------------------------------------------
// R18 = resubmission of R17 (container failure last round, no signal).
// R17 = R14 restored (the session's best: 69.5 us main / 159.8 bench), with:
//  - s_setprio REMOVED (only never-isolated knob; m190: setprio is mildly
//    negative in lockstep barrier-synced structures like this one).
//  - __launch_bounds__(512, 4): R12-proven identical outcome, full 128-reg
//    headroom -> zero spill risk.
// Everything else byte-identical to R14: frag layouts, ring-4 distance-2
// A-prefetch, peeled-p1 overlap, lgkm-only raw barriers, XCD swizzle.
template <bool F16P>
__global__ __launch_bounds__(512, 4) void fp_mfma16(
    const float* __restrict__ xyz1, const float* __restrict__ xyz2,
    const float* __restrict__ p1,   const float* __restrict__ p2,
    const float* __restrict__ W1,   const float* __restrict__ b1v,
    const float* __restrict__ W2,   const float* __restrict__ b2v,
    const _Float16* __restrict__ p2s, const _Float16* __restrict__ W1s,
    const _Float16* __restrict__ W2s,
    float* __restrict__ out)
{
    __shared__ __align__(16) char smem[SMEM_BYTES];
    _Float16* s_inv  = (_Float16*)smem;
    _Float16* s_X    = (_Float16*)smem;
    _Float16* s_H    = (_Float16*)smem;
    float*    s_xyz2 = (float*)(smem + OFF_XYZ2);
    float*    s_red  = (float*)(smem + OFF_RED);

    const int tid  = threadIdx.x;
    const int w    = tid >> 6;    // wave 0..7
    const int L    = tid & 63;
    const int quad = L >> 4;
    const int l16  = L & 15;

    // XCD swizzle: each XCD sees 2 batches -> p2s working set (1 MB) L2-resident
    const int id = blockIdx.x;            // 1024 blocks
    const int b  = (id & 7) * 2 + ((id >> 3) & 1);
    const int n0 = (id >> 4) * TN;

    const float* __restrict__ z2b = xyz2 + (size_t)b * MPTS * 3;
    const float* __restrict__ p2b = p2   + (size_t)b * C2c * MPTS;
    const _Float16* __restrict__ p2sb =
        F16P ? (p2s + (((size_t)b * 32 * 16 + (size_t)w * 2) * 64 + L) * 8) : (const _Float16*)nullptr;

    // stage xyz2 (12 KB, coalesced f32x4)
    for (int i = tid; i < MPTS * 3 / 4; i += 512)
        ((f32x4*)s_xyz2)[i] = ((const f32x4*)z2b)[i];

    const float x1x = xyz1[((size_t)b * NPTS + n0 + L) * 3 + 0];
    const float x1y = xyz1[((size_t)b * NPTS + n0 + L) * 3 + 1];
    const float x1z = xyz1[((size_t)b * NPTS + n0 + L) * 3 + 2];

    f32x4 acc[2][4];   // [ct][nt]: row c = w*32+ct*16+quad*4+r, col n = nt*16+l16
    #pragma unroll
    for (int ct = 0; ct < 2; ++ct)
        #pragma unroll
        for (int nt = 0; nt < 4; ++nt)
            acc[ct][nt] = (f32x4){0.f, 0.f, 0.f, 0.f};

    float ssum = 0.f;
    f16x8 Aa[4][2];    // A-frag ring, slot = chunk & 3 (prefetch distance 2)

    auto loadA = [&](int s, f16x8 dst[2]) {
        if (F16P) {
            const _Float16* ap = p2sb + (size_t)s * (16 * 64 * 8);
            #pragma unroll
            for (int ct = 0; ct < 2; ++ct)
                dst[ct] = *(const f16x8*)(ap + (size_t)ct * (64 * 8));
        } else {
            const float* ap = p2b + (size_t)(w * 32 + l16) * MPTS + s * 32 + quad * 8;
            #pragma unroll
            for (int ct = 0; ct < 2; ++ct) {
                const float4 a0 = *(const float4*)(ap + (size_t)ct * (16 * MPTS));
                const float4 a1 = *(const float4*)(ap + (size_t)ct * (16 * MPTS) + 4);
                f16x8 h;
                h[0] = (_Float16)a0.x; h[1] = (_Float16)a0.y; h[2] = (_Float16)a0.z; h[3] = (_Float16)a0.w;
                h[4] = (_Float16)a1.x; h[5] = (_Float16)a1.y; h[6] = (_Float16)a1.z; h[7] = (_Float16)a1.w;
                dst[ct] = h;
            }
        }
    };

    // one 8-m group of super-chunk ss_ into frag buffer (ss_&1), g in {0,1}:
    // thread (w,L): n=L, m = ss_*128 + w*16 + g*8 + i
    //   -> frag (cc = w>>1, nt = quad), k-slot q' = (w&1)*2+g, lane l16.
    auto gen_g = [&](int ss_, int g) {
        _Float16* buf = s_inv + (ss_ & 1) * INV_HALF;
        const float* zp = s_xyz2 + (size_t)(ss_ * 128 + w * 16 + g * 8) * 3;
        f32x4 zr[6];
        #pragma unroll
        for (int j = 0; j < 6; ++j) zr[j] = ((const f32x4*)zp)[j];
        const float* zv = (const float*)zr;
        f16x8 iv;
        #pragma unroll
        for (int i = 0; i < 8; ++i) {
            const float dx = x1x - zv[3 * i + 0];
            const float dy = x1y - zv[3 * i + 1];
            const float dz = x1z - zv[3 * i + 2];
            const float d2 = fmaf(dx, dx, fmaf(dy, dy, fmaf(dz, dz, 1e-12f)));
            const float inv = __builtin_amdgcn_rsqf(d2);
            ssum += inv;
            iv[i] = (_Float16)inv;
        }
        *(f16x8*)(buf + ((((w >> 1) * 4 + quad) * 64) + ((w & 1) * 2 + g) * 16 + l16) * 8) = iv;
    };

    loadA(0, Aa[0]);
    loadA(1, Aa[1]);
    BAR();             // xyz2 staged (lgkm drain; A-prefetch stays in flight)
    gen_g(0, 0);
    gen_g(0, 1);
    BAR();             // super-chunk 0 visible

    // ---- main phase-A loop: ss = 0..6 (ss = 7 peeled below) ----
    for (int ss = 0; ss < 7; ++ss) {
        const _Float16* buf = s_inv + (ss & 1) * INV_HALF;
        #pragma unroll
        for (int cc = 0; cc < 4; ++cc) {
            const int s = ss * 4 + cc;
            loadA(s + 2, Aa[(cc + 2) & 3]);   // distance-2 ring prefetch (s+2 <= 29)
            if (cc < 2) gen_g(ss + 1, cc);    // inv VALU interleaved
            #pragma unroll
            for (int nt = 0; nt < 4; ++nt) {
                const f16x8 bf = *(const f16x8*)(buf + ((cc * 4 + nt) * 64 + L) * 8);
                #pragma unroll
                for (int ct = 0; ct < 2; ++ct)
                    acc[ct][nt] = __builtin_amdgcn_mfma_f32_16x16x32_f16(Aa[cc][ct], bf, acc[ct][nt], 0, 0, 0);
            }
        }
        BAR();   // reads of buf(ss) done; writes of buf(ss+1) done; vm loads live
    }

    // ---- peeled ss = 7: p1 loads issued first, hidden under the MFMAs ----
    float tv[2][8];
    {
        #pragma unroll
        for (int h = 0; h < 2; ++h) {
            const int f  = w * 2 + h;      // 0..15
            const int kq = f >> 2, nt = f & 3;
            const float* pp = p1 + ((size_t)b * C1c + kq * 32 + quad * 8) * NPTS + n0 + nt * 16 + l16;
            #pragma unroll
            for (int j = 0; j < 8; ++j) tv[h][j] = pp[(size_t)j * NPTS];
        }
    }
    {
        const _Float16* buf = s_inv + INV_HALF;   // 7 & 1 = 1
        #pragma unroll
        for (int cc = 0; cc < 4; ++cc) {
            if (cc < 2) loadA(28 + cc + 2, Aa[(cc + 2) & 3]);   // chunks 30, 31
            #pragma unroll
            for (int nt = 0; nt < 4; ++nt) {
                const f16x8 bf = *(const f16x8*)(buf + ((cc * 4 + nt) * 64 + L) * 8);
                #pragma unroll
                for (int ct = 0; ct < 2; ++ct)
                    acc[ct][nt] = __builtin_amdgcn_mfma_f32_16x16x32_f16(Aa[cc][ct], bf, acc[ct][nt], 0, 0, 0);
            }
        }
    }
    // p1 -> s_X frags kq 0..3 (bytes [0,16K) = buf0; its last reads were ss=6,
    // drained at that barrier). ssum store: s_red is outside the union.
    {
        #pragma unroll
        for (int h = 0; h < 2; ++h) {
            const int f = w * 2 + h;
            f16x8 v;
            #pragma unroll
            for (int j = 0; j < 8; ++j) v[j] = (_Float16)tv[h][j];
            *(f16x8*)(s_X + ((size_t)f * 64 + L) * 8) = v;
        }
    }
    s_red[tid] = ssum;
    BAR();

    // ---- recip over the 8 m-slice partials
    if (tid < 64) {
        float s = 0.f;
        #pragma unroll
        for (int wv = 0; wv < 8; ++wv) s += s_red[wv * 64 + tid];
        s_red[tid] = 1.0f / s;
    }
    BAR();   // recip ready; phase-A scratch dead -> interp overlay safe

    // phase-B prefetch issued now: flies across the interp work + barrier
    f16x8 afP[2][2];
    auto loadW1 = [&](int kc, f16x8 dst[2]) {
        if (F16P) {
            const _Float16* wp = W1s + (((size_t)(w * 2) * 12 + kc) * 64 + L) * 8;
            #pragma unroll
            for (int ct = 0; ct < 2; ++ct)
                dst[ct] = *(const f16x8*)(wp + (size_t)ct * (12 * 64 * 8));
        } else {
            const float* wp = W1 + (size_t)(w * 32 + l16) * CINc + kc * 32 + quad * 8;
            #pragma unroll
            for (int ct = 0; ct < 2; ++ct) {
                const float4 a0 = *(const float4*)(wp + ct * (16 * CINc));
                const float4 a1 = *(const float4*)(wp + ct * (16 * CINc) + 4);
                f16x8 h;
                h[0] = (_Float16)a0.x; h[1] = (_Float16)a0.y; h[2] = (_Float16)a0.z; h[3] = (_Float16)a0.w;
                h[4] = (_Float16)a1.x; h[5] = (_Float16)a1.y; h[6] = (_Float16)a1.z; h[7] = (_Float16)a1.w;
                dst[ct] = h;
            }
        }
    };
    loadW1(0, afP[0]);

    // interp -> s_X frags kq = 4 + w (bytes [16K,48K): dead buf1 + dead xyz2).
    {
        float rn4[4];
        #pragma unroll
        for (int nt = 0; nt < 4; ++nt) rn4[nt] = s_red[nt * 16 + l16];
        #pragma unroll
        for (int ct = 0; ct < 2; ++ct) {
            const int kq = 4 + w;
            const int lp = (ct * 2 + (quad >> 1)) * 16 + l16;
            const int jo = (quad & 1) * 4;
            #pragma unroll
            for (int nt = 0; nt < 4; ++nt) {
                const f32x4 v = acc[ct][nt];
                const float r = rn4[nt];
                f16x4 hv;
                hv[0] = (_Float16)(v[0] * r);
                hv[1] = (_Float16)(v[1] * r);
                hv[2] = (_Float16)(v[2] * r);
                hv[3] = (_Float16)(v[3] * r);
                *(f16x4*)(s_X + (((size_t)(kq * 4 + nt)) * 64 + lp) * 8 + jo) = hv;
            }
        }
    }
    BAR();   // full X (p1 + interp) frags complete; W1 frag-0 still in flight

    // ---------------- Phase B: h = relu(W1 @ X + b1), K=384 ----------------
    f32x4 hacc[2][4];
    #pragma unroll
    for (int ct = 0; ct < 2; ++ct)
        #pragma unroll
        for (int nt = 0; nt < 4; ++nt)
            hacc[ct][nt] = (f32x4){0.f, 0.f, 0.f, 0.f};

    #pragma unroll
    for (int kc = 0; kc < 12; ++kc) {
        if (kc + 1 < 12) loadW1(kc + 1, afP[(kc + 1) & 1]);
        #pragma unroll
        for (int nt = 0; nt < 4; ++nt) {
            const f16x8 bf = *(const f16x8*)(s_X + (((size_t)(kc * 4 + nt)) * 64 + L) * 8);
            #pragma unroll
            for (int ct = 0; ct < 2; ++ct)
                hacc[ct][nt] = __builtin_amdgcn_mfma_f32_16x16x32_f16(afP[kc & 1][ct], bf, hacc[ct][nt], 0, 0, 0);
        }
    }

    BAR();   // all s_X reads done before overlaying s_H

    // phase-C prefetch issued now: flies across h-stage + barrier
    f16x8 afP2[2];
    auto loadW2 = [&](int oc, f16x8& dst) {
        if (F16P) {
            dst = *(const f16x8*)(W2s + (((size_t)(w * 8 + oc)) * 64 + L) * 8);
        } else {
            const float* wp = W2 + (size_t)(w * 16 + l16) * H1c + oc * 32 + quad * 8;
            const float4 a0 = *(const float4*)(wp);
            const float4 a1 = *(const float4*)(wp + 4);
            f16x8 h;
            h[0] = (_Float16)a0.x; h[1] = (_Float16)a0.y; h[2] = (_Float16)a0.z; h[3] = (_Float16)a0.w;
            h[4] = (_Float16)a1.x; h[5] = (_Float16)a1.y; h[6] = (_Float16)a1.z; h[7] = (_Float16)a1.w;
            dst = h;
        }
    };
    loadW2(0, afP2[0]);

    // bias + relu + stage h -> s_H frag layout (oq = w, same slot math as interp)
    {
        f32x4 bb[2];
        #pragma unroll
        for (int ct = 0; ct < 2; ++ct)
            bb[ct] = *(const f32x4*)(b1v + w * 32 + ct * 16 + quad * 4);
        #pragma unroll
        for (int ct = 0; ct < 2; ++ct) {
            const int lp = (ct * 2 + (quad >> 1)) * 16 + l16;
            const int jo = (quad & 1) * 4;
            #pragma unroll
            for (int nt = 0; nt < 4; ++nt) {
                const f32x4 v = hacc[ct][nt];
                f16x4 hv;
                hv[0] = (_Float16)fmaxf(v[0] + bb[ct][0], 0.f);
                hv[1] = (_Float16)fmaxf(v[1] + bb[ct][1], 0.f);
                hv[2] = (_Float16)fmaxf(v[2] + bb[ct][2], 0.f);
                hv[3] = (_Float16)fmaxf(v[3] + bb[ct][3], 0.f);
                *(f16x4*)(s_H + (((size_t)(w * 4 + nt)) * 64 + lp) * 8 + jo) = hv;
            }
        }
    }
    BAR();

    // ---------------- Phase C: out = relu(W2 @ h + b2), K=256 --------------
    f32x4 oacc[4];
    #pragma unroll
    for (int nt = 0; nt < 4; ++nt)
        oacc[nt] = (f32x4){0.f, 0.f, 0.f, 0.f};

    #pragma unroll
    for (int oc = 0; oc < 8; ++oc) {
        if (oc + 1 < 8) loadW2(oc + 1, afP2[(oc + 1) & 1]);
        #pragma unroll
        for (int nt = 0; nt < 4; ++nt) {
            const f16x8 bf = *(const f16x8*)(s_H + (((size_t)(oc * 4 + nt)) * 64 + L) * 8);
            oacc[nt] = __builtin_amdgcn_mfma_f32_16x16x32_f16(afP2[oc & 1], bf, oacc[nt], 0, 0, 0);
        }
    }

    // epilogue: bias + relu + store (o = w*16 + quad*4 + j)
    {
        const f32x4 bb2 = *(const f32x4*)(b2v + w * 16 + quad * 4);
        #pragma unroll
        for (int nt = 0; nt < 4; ++nt) {
            float* op = out + ((size_t)b * H2c + w * 16 + quad * 4) * NPTS
                            + n0 + nt * 16 + l16;
            #pragma unroll
            for (int j = 0; j < 4; ++j)
                op[(size_t)j * NPTS] = fmaxf(oacc[nt][j] + bb2[j], 0.f);
        }
    }
}

extern "C" void kernel_launch(void* const* d_in, const int* in_sizes, int n_in,
                              void* d_out, int out_size, void* d_ws, size_t ws_size,
                              hipStream_t stream) {
    (void)in_sizes; (void)n_in; (void)out_size;
    const float* xyz1 = (const float*)d_in[0];
    const float* xyz2 = (const float*)d_in[1];
    const float* p1   = (const float*)d_in[2];
    const float* p2   = (const float*)d_in[3];
    const float* W1   = (const float*)d_in[4];
    const float* b1   = (const float*)d_in[5];
    const float* W2   = (const float*)d_in[6];
    const float* b2   = (const float*)d_in[7];
    float* out = (float*)d_out;

    dim3 grid(BBATCH * (NPTS / TN));   // 1024 blocks @ 2 resident/CU
    dim3 block(512);
    if (ws_size >= (size_t)WS_F16_TOTAL * 2) {
        _Float16* ws = (_Float16*)d_ws;
        const int nswz = NFRAG_P2 + NFRAG_W1 + NFRAG_W2;   // 540672 = 2112 * 256
        cvt_swz<<<dim3(nswz / 256), dim3(256), 0, stream>>>(p2, W1, W2, ws);
        fp_mfma16<true><<<grid, block, 0, stream>>>(xyz1, xyz2, p1, p2, W1, b1, W2, b2,
                                                    ws + WS_P2S, ws + WS_W1S, ws + WS_W2S, out);
    } else {
        fp_mfma16<false><<<grid, block, 0, stream>>>(xyz1, xyz2, p1, p2, W1, b1, W2, b2,
                                                     nullptr, nullptr, nullptr, out);
    }
}

// Round 11
// 160.467 us; speedup vs baseline: 3.1641x; 1.0375x over previous
//
#include <hip/hip_runtime.h>
#include <math.h>

// Problem constants (from reference setup_inputs)
#define BBATCH 16
#define NPTS   4096
#define MPTS   1024
#define C1c    128
#define C2c    256
#define CINc   384
#define H1c    256
#define H2c    128
#define TN     64

typedef _Float16 f16x8 __attribute__((ext_vector_type(8)));
typedef _Float16 f16x4 __attribute__((ext_vector_type(4)));
typedef float    f32x4 __attribute__((ext_vector_type(4)));

// Raw barrier: drain LDS ops only; global prefetch loads stay in flight.
#define BAR() do { asm volatile("s_waitcnt lgkmcnt(0)" ::: "memory"); \
                   __builtin_amdgcn_s_barrier(); } while (0)

// ---- LDS layout (bytes) ---------------------------------------------------
// union [0,49152):
//   phase A: inv dbuf 2 x [4 cc][4 nt][64 lane][8 f16] = 32768 B
//            s_xyz2 [1024][3] f32 = 12288 B at 32768 (dead after last gen)
//   phase B: s_X frags [12 kc][4 nt][64][8] f16 = 49152 B
//   phase C: s_H frags [8 oc][4 nt][64][8] f16 = 32768 B
// s_red 512 f32 at 49152 (recip overlaid in first 64)
// Total 51200 B -> 2 blocks/CU, 16 waves/CU.
//
// SESSION LESSONS BAKED IN (do not perturb):
//  - This kernel lives ~10 regs from the spill cliff. R8/(256,4), R10/ring+2tile,
//    R16/restructure, R18/setprio-removal ALL spilled or regressed via codegen
//    shifts. R14's exact shape (VGPR 52, WRITE 32.77 MB) is the proven optimum.
//  - s_setprio REQUIRED here: removing it (R18) let the scheduler extend live
//    ranges -> VGPR 64 + 8 MB spill + 4.3 us. It acts as a region fence.
//  - __launch_bounds__(512,8) with this code compiles to 52 VGPR, no spill (R14).
//  - Occupancy is pinned at 16 waves/CU (LDS from above, spill from below);
//    barrier count/prefetch depth/chunk size are all flat at this concurrency.
#define INV_HALF   8192            // f16 elems per inv buffer (16384 B)
#define OFF_XYZ2   32768
#define OFF_RED    49152
#define SMEM_BYTES 51200

// ---- fragment-swizzled workspace layout (f16 elements), unchanged ----
#define NFRAG_P2  (BBATCH * 32 * 16 * 64)        // 524288
#define NFRAG_W1  (16 * 12 * 64)                 // 12288
#define NFRAG_W2  (8 * 8 * 64)                   // 4096
#define WS_P2S  0
#define WS_W1S  (NFRAG_P2 * 8)                   // 4194304
#define WS_W2S  (WS_W1S + NFRAG_W1 * 8)
#define WS_F16_TOTAL (WS_W2S + NFRAG_W2 * 8)     // 4325376 f16 = 8650752 B

// ---------------------------------------------------------------------------
// pre-pass: convert + swizzle p2 / W1 / W2 into fragment-contiguous f16
__global__ __launch_bounds__(256) void cvt_swz(
    const float* __restrict__ p2, const float* __restrict__ W1,
    const float* __restrict__ W2, _Float16* __restrict__ ws)
{
    const int t = blockIdx.x * 256 + threadIdx.x;   // one fragment (8 f16) per thread
    const float* src;
    _Float16* dst;
    if (t < NFRAG_P2) {
        const int lane = t & 63, wt = (t >> 6) & 15, s = (t >> 10) & 31, b = t >> 15;
        const int c = wt * 16 + (lane & 15);
        const int m = s * 32 + (lane >> 4) * 8;
        src = p2 + ((size_t)(b * C2c + c)) * MPTS + m;
        dst = ws + WS_P2S + (size_t)t * 8;
    } else if (t < NFRAG_P2 + NFRAG_W1) {
        const int u = t - NFRAG_P2;
        const int lane = u & 63, kc = (u >> 6) % 12, wt = (u >> 6) / 12;
        const int o = wt * 16 + (lane & 15);
        const int k = kc * 32 + (lane >> 4) * 8;
        src = W1 + (size_t)o * CINc + k;
        dst = ws + WS_W1S + (size_t)u * 8;
    } else {
        const int v = t - NFRAG_P2 - NFRAG_W1;
        const int lane = v & 63, oc = (v >> 6) & 7, wt2 = v >> 9;
        const int o = wt2 * 16 + (lane & 15);
        const int k = oc * 32 + (lane >> 4) * 8;
        src = W2 + (size_t)o * H1c + k;
        dst = ws + WS_W2S + (size_t)v * 8;
    }
    const float4 a0 = *(const float4*)(src);
    const float4 a1 = *(const float4*)(src + 4);
    f16x8 h;
    h[0] = (_Float16)a0.x; h[1] = (_Float16)a0.y; h[2] = (_Float16)a0.z; h[3] = (_Float16)a0.w;
    h[4] = (_Float16)a1.x; h[5] = (_Float16)a1.y; h[6] = (_Float16)a1.z; h[7] = (_Float16)a1.w;
    *(f16x8*)dst = h;
}

// ---------------------------------------------------------------------------
// R19 = byte-identical restore of R14, the session's best measured kernel
// (main 69.4-70.3 us, bench 159.8 us): R12 dataflow + __launch_bounds__(512,8)
// + s_setprio around MFMA clusters. Frag-contiguous LDS everywhere, ring-4
// distance-2 A-prefetch, peeled-p1 overlap, lgkm-only raw barriers, XCD swizzle.
template <bool F16P>
__global__ __launch_bounds__(512, 8) void fp_mfma14(
    const float* __restrict__ xyz1, const float* __restrict__ xyz2,
    const float* __restrict__ p1,   const float* __restrict__ p2,
    const float* __restrict__ W1,   const float* __restrict__ b1v,
    const float* __restrict__ W2,   const float* __restrict__ b2v,
    const _Float16* __restrict__ p2s, const _Float16* __restrict__ W1s,
    const _Float16* __restrict__ W2s,
    float* __restrict__ out)
{
    __shared__ __align__(16) char smem[SMEM_BYTES];
    _Float16* s_inv  = (_Float16*)smem;
    _Float16* s_X    = (_Float16*)smem;
    _Float16* s_H    = (_Float16*)smem;
    float*    s_xyz2 = (float*)(smem + OFF_XYZ2);
    float*    s_red  = (float*)(smem + OFF_RED);

    const int tid  = threadIdx.x;
    const int w    = tid >> 6;    // wave 0..7
    const int L    = tid & 63;
    const int quad = L >> 4;
    const int l16  = L & 15;

    // XCD swizzle: each XCD sees 2 batches -> p2s working set (1 MB) L2-resident
    const int id = blockIdx.x;            // 1024 blocks
    const int b  = (id & 7) * 2 + ((id >> 3) & 1);
    const int n0 = (id >> 4) * TN;

    const float* __restrict__ z2b = xyz2 + (size_t)b * MPTS * 3;
    const float* __restrict__ p2b = p2   + (size_t)b * C2c * MPTS;
    const _Float16* __restrict__ p2sb =
        F16P ? (p2s + (((size_t)b * 32 * 16 + (size_t)w * 2) * 64 + L) * 8) : (const _Float16*)nullptr;

    // stage xyz2 (12 KB, coalesced f32x4)
    for (int i = tid; i < MPTS * 3 / 4; i += 512)
        ((f32x4*)s_xyz2)[i] = ((const f32x4*)z2b)[i];

    const float x1x = xyz1[((size_t)b * NPTS + n0 + L) * 3 + 0];
    const float x1y = xyz1[((size_t)b * NPTS + n0 + L) * 3 + 1];
    const float x1z = xyz1[((size_t)b * NPTS + n0 + L) * 3 + 2];

    f32x4 acc[2][4];   // [ct][nt]: row c = w*32+ct*16+quad*4+r, col n = nt*16+l16
    #pragma unroll
    for (int ct = 0; ct < 2; ++ct)
        #pragma unroll
        for (int nt = 0; nt < 4; ++nt)
            acc[ct][nt] = (f32x4){0.f, 0.f, 0.f, 0.f};

    float ssum = 0.f;
    f16x8 Aa[4][2];    // A-frag ring, slot = chunk & 3 (prefetch distance 2)

    auto loadA = [&](int s, f16x8 dst[2]) {
        if (F16P) {
            const _Float16* ap = p2sb + (size_t)s * (16 * 64 * 8);
            #pragma unroll
            for (int ct = 0; ct < 2; ++ct)
                dst[ct] = *(const f16x8*)(ap + (size_t)ct * (64 * 8));
        } else {
            const float* ap = p2b + (size_t)(w * 32 + l16) * MPTS + s * 32 + quad * 8;
            #pragma unroll
            for (int ct = 0; ct < 2; ++ct) {
                const float4 a0 = *(const float4*)(ap + (size_t)ct * (16 * MPTS));
                const float4 a1 = *(const float4*)(ap + (size_t)ct * (16 * MPTS) + 4);
                f16x8 h;
                h[0] = (_Float16)a0.x; h[1] = (_Float16)a0.y; h[2] = (_Float16)a0.z; h[3] = (_Float16)a0.w;
                h[4] = (_Float16)a1.x; h[5] = (_Float16)a1.y; h[6] = (_Float16)a1.z; h[7] = (_Float16)a1.w;
                dst[ct] = h;
            }
        }
    };

    // one 8-m group of super-chunk ss_ into frag buffer (ss_&1), g in {0,1}:
    // thread (w,L): n=L, m = ss_*128 + w*16 + g*8 + i
    //   -> frag (cc = w>>1, nt = quad), k-slot q' = (w&1)*2+g, lane l16.
    auto gen_g = [&](int ss_, int g) {
        _Float16* buf = s_inv + (ss_ & 1) * INV_HALF;
        const float* zp = s_xyz2 + (size_t)(ss_ * 128 + w * 16 + g * 8) * 3;
        f32x4 zr[6];
        #pragma unroll
        for (int j = 0; j < 6; ++j) zr[j] = ((const f32x4*)zp)[j];
        const float* zv = (const float*)zr;
        f16x8 iv;
        #pragma unroll
        for (int i = 0; i < 8; ++i) {
            const float dx = x1x - zv[3 * i + 0];
            const float dy = x1y - zv[3 * i + 1];
            const float dz = x1z - zv[3 * i + 2];
            const float d2 = fmaf(dx, dx, fmaf(dy, dy, fmaf(dz, dz, 1e-12f)));
            const float inv = __builtin_amdgcn_rsqf(d2);
            ssum += inv;
            iv[i] = (_Float16)inv;
        }
        *(f16x8*)(buf + ((((w >> 1) * 4 + quad) * 64) + ((w & 1) * 2 + g) * 16 + l16) * 8) = iv;
    };

    loadA(0, Aa[0]);
    loadA(1, Aa[1]);
    BAR();             // xyz2 staged (lgkm drain; A-prefetch stays in flight)
    gen_g(0, 0);
    gen_g(0, 1);
    BAR();             // super-chunk 0 visible

    // ---- main phase-A loop: ss = 0..6 (ss = 7 peeled below) ----
    for (int ss = 0; ss < 7; ++ss) {
        const _Float16* buf = s_inv + (ss & 1) * INV_HALF;
        #pragma unroll
        for (int cc = 0; cc < 4; ++cc) {
            const int s = ss * 4 + cc;
            loadA(s + 2, Aa[(cc + 2) & 3]);   // distance-2 ring prefetch (s+2 <= 29)
            if (cc < 2) gen_g(ss + 1, cc);    // inv VALU interleaved
            __builtin_amdgcn_s_setprio(1);
            #pragma unroll
            for (int nt = 0; nt < 4; ++nt) {
                const f16x8 bf = *(const f16x8*)(buf + ((cc * 4 + nt) * 64 + L) * 8);
                #pragma unroll
                for (int ct = 0; ct < 2; ++ct)
                    acc[ct][nt] = __builtin_amdgcn_mfma_f32_16x16x32_f16(Aa[cc][ct], bf, acc[ct][nt], 0, 0, 0);
            }
            __builtin_amdgcn_s_setprio(0);
        }
        BAR();   // reads of buf(ss) done; writes of buf(ss+1) done; vm loads live
    }

    // ---- peeled ss = 7: p1 loads issued first, hidden under the MFMAs ----
    float tv[2][8];
    {
        #pragma unroll
        for (int h = 0; h < 2; ++h) {
            const int f  = w * 2 + h;      // 0..15
            const int kq = f >> 2, nt = f & 3;
            const float* pp = p1 + ((size_t)b * C1c + kq * 32 + quad * 8) * NPTS + n0 + nt * 16 + l16;
            #pragma unroll
            for (int j = 0; j < 8; ++j) tv[h][j] = pp[(size_t)j * NPTS];
        }
    }
    {
        const _Float16* buf = s_inv + INV_HALF;   // 7 & 1 = 1
        #pragma unroll
        for (int cc = 0; cc < 4; ++cc) {
            if (cc < 2) loadA(28 + cc + 2, Aa[(cc + 2) & 3]);   // chunks 30, 31
            __builtin_amdgcn_s_setprio(1);
            #pragma unroll
            for (int nt = 0; nt < 4; ++nt) {
                const f16x8 bf = *(const f16x8*)(buf + ((cc * 4 + nt) * 64 + L) * 8);
                #pragma unroll
                for (int ct = 0; ct < 2; ++ct)
                    acc[ct][nt] = __builtin_amdgcn_mfma_f32_16x16x32_f16(Aa[cc][ct], bf, acc[ct][nt], 0, 0, 0);
            }
            __builtin_amdgcn_s_setprio(0);
        }
    }
    // p1 -> s_X frags kq 0..3 (bytes [0,16K) = buf0; its last reads were ss=6,
    // drained at that barrier). ssum store: s_red is outside the union.
    {
        #pragma unroll
        for (int h = 0; h < 2; ++h) {
            const int f = w * 2 + h;
            f16x8 v;
            #pragma unroll
            for (int j = 0; j < 8; ++j) v[j] = (_Float16)tv[h][j];
            *(f16x8*)(s_X + ((size_t)f * 64 + L) * 8) = v;
        }
    }
    s_red[tid] = ssum;
    BAR();

    // ---- recip over the 8 m-slice partials
    if (tid < 64) {
        float s = 0.f;
        #pragma unroll
        for (int wv = 0; wv < 8; ++wv) s += s_red[wv * 64 + tid];
        s_red[tid] = 1.0f / s;
    }
    BAR();   // recip ready; phase-A scratch dead -> interp overlay safe

    // phase-B prefetch issued now: flies across the interp work + barrier
    f16x8 afP[2][2];
    auto loadW1 = [&](int kc, f16x8 dst[2]) {
        if (F16P) {
            const _Float16* wp = W1s + (((size_t)(w * 2) * 12 + kc) * 64 + L) * 8;
            #pragma unroll
            for (int ct = 0; ct < 2; ++ct)
                dst[ct] = *(const f16x8*)(wp + (size_t)ct * (12 * 64 * 8));
        } else {
            const float* wp = W1 + (size_t)(w * 32 + l16) * CINc + kc * 32 + quad * 8;
            #pragma unroll
            for (int ct = 0; ct < 2; ++ct) {
                const float4 a0 = *(const float4*)(wp + ct * (16 * CINc));
                const float4 a1 = *(const float4*)(wp + ct * (16 * CINc) + 4);
                f16x8 h;
                h[0] = (_Float16)a0.x; h[1] = (_Float16)a0.y; h[2] = (_Float16)a0.z; h[3] = (_Float16)a0.w;
                h[4] = (_Float16)a1.x; h[5] = (_Float16)a1.y; h[6] = (_Float16)a1.z; h[7] = (_Float16)a1.w;
                dst[ct] = h;
            }
        }
    };
    loadW1(0, afP[0]);

    // interp -> s_X frags kq = 4 + w (bytes [16K,48K): dead buf1 + dead xyz2).
    {
        float rn4[4];
        #pragma unroll
        for (int nt = 0; nt < 4; ++nt) rn4[nt] = s_red[nt * 16 + l16];
        #pragma unroll
        for (int ct = 0; ct < 2; ++ct) {
            const int kq = 4 + w;
            const int lp = (ct * 2 + (quad >> 1)) * 16 + l16;
            const int jo = (quad & 1) * 4;
            #pragma unroll
            for (int nt = 0; nt < 4; ++nt) {
                const f32x4 v = acc[ct][nt];
                const float r = rn4[nt];
                f16x4 hv;
                hv[0] = (_Float16)(v[0] * r);
                hv[1] = (_Float16)(v[1] * r);
                hv[2] = (_Float16)(v[2] * r);
                hv[3] = (_Float16)(v[3] * r);
                *(f16x4*)(s_X + (((size_t)(kq * 4 + nt)) * 64 + lp) * 8 + jo) = hv;
            }
        }
    }
    BAR();   // full X (p1 + interp) frags complete; W1 frag-0 still in flight

    // ---------------- Phase B: h = relu(W1 @ X + b1), K=384 ----------------
    f32x4 hacc[2][4];
    #pragma unroll
    for (int ct = 0; ct < 2; ++ct)
        #pragma unroll
        for (int nt = 0; nt < 4; ++nt)
            hacc[ct][nt] = (f32x4){0.f, 0.f, 0.f, 0.f};

    #pragma unroll
    for (int kc = 0; kc < 12; ++kc) {
        if (kc + 1 < 12) loadW1(kc + 1, afP[(kc + 1) & 1]);
        __builtin_amdgcn_s_setprio(1);
        #pragma unroll
        for (int nt = 0; nt < 4; ++nt) {
            const f16x8 bf = *(const f16x8*)(s_X + (((size_t)(kc * 4 + nt)) * 64 + L) * 8);
            #pragma unroll
            for (int ct = 0; ct < 2; ++ct)
                hacc[ct][nt] = __builtin_amdgcn_mfma_f32_16x16x32_f16(afP[kc & 1][ct], bf, hacc[ct][nt], 0, 0, 0);
        }
        __builtin_amdgcn_s_setprio(0);
    }

    BAR();   // all s_X reads done before overlaying s_H

    // phase-C prefetch issued now: flies across h-stage + barrier
    f16x8 afP2[2];
    auto loadW2 = [&](int oc, f16x8& dst) {
        if (F16P) {
            dst = *(const f16x8*)(W2s + (((size_t)(w * 8 + oc)) * 64 + L) * 8);
        } else {
            const float* wp = W2 + (size_t)(w * 16 + l16) * H1c + oc * 32 + quad * 8;
            const float4 a0 = *(const float4*)(wp);
            const float4 a1 = *(const float4*)(wp + 4);
            f16x8 h;
            h[0] = (_Float16)a0.x; h[1] = (_Float16)a0.y; h[2] = (_Float16)a0.z; h[3] = (_Float16)a0.w;
            h[4] = (_Float16)a1.x; h[5] = (_Float16)a1.y; h[6] = (_Float16)a1.z; h[7] = (_Float16)a1.w;
            dst = h;
        }
    };
    loadW2(0, afP2[0]);

    // bias + relu + stage h -> s_H frag layout (oq = w, same slot math as interp)
    {
        f32x4 bb[2];
        #pragma unroll
        for (int ct = 0; ct < 2; ++ct)
            bb[ct] = *(const f32x4*)(b1v + w * 32 + ct * 16 + quad * 4);
        #pragma unroll
        for (int ct = 0; ct < 2; ++ct) {
            const int lp = (ct * 2 + (quad >> 1)) * 16 + l16;
            const int jo = (quad & 1) * 4;
            #pragma unroll
            for (int nt = 0; nt < 4; ++nt) {
                const f32x4 v = hacc[ct][nt];
                f16x4 hv;
                hv[0] = (_Float16)fmaxf(v[0] + bb[ct][0], 0.f);
                hv[1] = (_Float16)fmaxf(v[1] + bb[ct][1], 0.f);
                hv[2] = (_Float16)fmaxf(v[2] + bb[ct][2], 0.f);
                hv[3] = (_Float16)fmaxf(v[3] + bb[ct][3], 0.f);
                *(f16x4*)(s_H + (((size_t)(w * 4 + nt)) * 64 + lp) * 8 + jo) = hv;
            }
        }
    }
    BAR();

    // ---------------- Phase C: out = relu(W2 @ h + b2), K=256 --------------
    f32x4 oacc[4];
    #pragma unroll
    for (int nt = 0; nt < 4; ++nt)
        oacc[nt] = (f32x4){0.f, 0.f, 0.f, 0.f};

    #pragma unroll
    for (int oc = 0; oc < 8; ++oc) {
        if (oc + 1 < 8) loadW2(oc + 1, afP2[(oc + 1) & 1]);
        __builtin_amdgcn_s_setprio(1);
        #pragma unroll
        for (int nt = 0; nt < 4; ++nt) {
            const f16x8 bf = *(const f16x8*)(s_H + (((size_t)(oc * 4 + nt)) * 64 + L) * 8);
            oacc[nt] = __builtin_amdgcn_mfma_f32_16x16x32_f16(afP2[oc & 1], bf, oacc[nt], 0, 0, 0);
        }
        __builtin_amdgcn_s_setprio(0);
    }

    // epilogue: bias + relu + store (o = w*16 + quad*4 + j)
    {
        const f32x4 bb2 = *(const f32x4*)(b2v + w * 16 + quad * 4);
        #pragma unroll
        for (int nt = 0; nt < 4; ++nt) {
            float* op = out + ((size_t)b * H2c + w * 16 + quad * 4) * NPTS
                            + n0 + nt * 16 + l16;
            #pragma unroll
            for (int j = 0; j < 4; ++j)
                op[(size_t)j * NPTS] = fmaxf(oacc[nt][j] + bb2[j], 0.f);
        }
    }
}

extern "C" void kernel_launch(void* const* d_in, const int* in_sizes, int n_in,
                              void* d_out, int out_size, void* d_ws, size_t ws_size,
                              hipStream_t stream) {
    (void)in_sizes; (void)n_in; (void)out_size;
    const float* xyz1 = (const float*)d_in[0];
    const float* xyz2 = (const float*)d_in[1];
    const float* p1   = (const float*)d_in[2];
    const float* p2   = (const float*)d_in[3];
    const float* W1   = (const float*)d_in[4];
    const float* b1   = (const float*)d_in[5];
    const float* W2   = (const float*)d_in[6];
    const float* b2   = (const float*)d_in[7];
    float* out = (float*)d_out;

    dim3 grid(BBATCH * (NPTS / TN));   // 1024 blocks @ 2 resident/CU
    dim3 block(512);
    if (ws_size >= (size_t)WS_F16_TOTAL * 2) {
        _Float16* ws = (_Float16*)d_ws;
        const int nswz = NFRAG_P2 + NFRAG_W1 + NFRAG_W2;   // 540672 = 2112 * 256
        cvt_swz<<<dim3(nswz / 256), dim3(256), 0, stream>>>(p2, W1, W2, ws);
        fp_mfma14<true><<<grid, block, 0, stream>>>(xyz1, xyz2, p1, p2, W1, b1, W2, b2,
                                                    ws + WS_P2S, ws + WS_W1S, ws + WS_W2S, out);
    } else {
        fp_mfma14<false><<<grid, block, 0, stream>>>(xyz1, xyz2, p1, p2, W1, b1, W2, b2,
                                                     nullptr, nullptr, nullptr, out);
    }
}